// Round 1
// baseline (17.919 us; speedup 1.0000x reference)
//
#include <hip/hip_runtime.h>

#define T_LEN 65536
// x: [T, B=2, DIN=4] f32 ; ih: [4,5] ; hh: [5,5] ; bias: [5] ; out: scalar f32
// out = sum_t sum_b (x_t[b]@ih + bias) @ hh^(T-1-t) @ ones
//     = sum_t ((sum_b x_t[b])@ih + 2*bias) . w_{T-1-t},  w_s = hh^s @ ones

__global__ __launch_bounds__(256) void elman_sum_kernel(
    const float* __restrict__ x, const float* __restrict__ ih,
    const float* __restrict__ hh, const float* __restrict__ bias,
    float* __restrict__ out)
{
    __shared__ float sP[16][25];   // sP[k] = hh^(2^k), row-major 5x5
    __shared__ float sih[20];      // ih row-major [4][5]
    __shared__ float sb[5];
    __shared__ float red[4];       // per-wave partials (256 threads = 4 waves)

    const int tid = threadIdx.x;
    if (tid < 25) sP[0][tid] = hh[tid];
    if (tid < 20) sih[tid]   = ih[tid];
    if (tid < 5)  sb[tid]    = bias[tid];
    __syncthreads();

    // repeated squaring: sP[k+1] = sP[k] @ sP[k]   (25 lanes, 5 FMAs each)
    for (int k = 0; k < 15; ++k) {
        float v = 0.f;
        if (tid < 25) {
            const int i = tid / 5, j = tid % 5;
            #pragma unroll
            for (int l = 0; l < 5; ++l) v += sP[k][i*5 + l] * sP[k][l*5 + j];
        }
        __syncthreads();
        if (tid < 25) sP[k+1][tid] = v;
        __syncthreads();
    }

    const int t = blockIdx.x * blockDim.x + tid;        // exactly covers [0, T)
    const unsigned s = (unsigned)(T_LEN - 1 - t);

    // w = hh^s @ ones via binary decomposition (branchless selects; sP reads
    // are wave-uniform -> LDS broadcast, no bank conflicts)
    float w0 = 1.f, w1 = 1.f, w2 = 1.f, w3 = 1.f, w4 = 1.f;
    #pragma unroll
    for (int k = 0; k < 16; ++k) {
        const float* P = sP[k];
        const float n0 = P[ 0]*w0 + P[ 1]*w1 + P[ 2]*w2 + P[ 3]*w3 + P[ 4]*w4;
        const float n1 = P[ 5]*w0 + P[ 6]*w1 + P[ 7]*w2 + P[ 8]*w3 + P[ 9]*w4;
        const float n2 = P[10]*w0 + P[11]*w1 + P[12]*w2 + P[13]*w3 + P[14]*w4;
        const float n3 = P[15]*w0 + P[16]*w1 + P[17]*w2 + P[18]*w3 + P[19]*w4;
        const float n4 = P[20]*w0 + P[21]*w1 + P[22]*w2 + P[23]*w3 + P[24]*w4;
        const bool take = (s >> k) & 1u;
        w0 = take ? n0 : w0;
        w1 = take ? n1 : w1;
        w2 = take ? n2 : w2;
        w3 = take ? n3 : w3;
        w4 = take ? n4 : w4;
    }

    // coalesced read of x[t] : 2 rows of 4 floats = 2x float4
    const float4* x4 = (const float4*)x;
    const float4 r0 = x4[2*t];
    const float4 r1 = x4[2*t + 1];
    const float xs0 = r0.x + r1.x, xs1 = r0.y + r1.y;
    const float xs2 = r0.z + r1.z, xs3 = r0.w + r1.w;

    // contrib = ((sum_b x_t[b])@ih + 2*bias) . w
    float contrib = 0.f;
    {
        const float u0 = 2.f*sb[0] + xs0*sih[0] + xs1*sih[5] + xs2*sih[10] + xs3*sih[15];
        const float u1 = 2.f*sb[1] + xs0*sih[1] + xs1*sih[6] + xs2*sih[11] + xs3*sih[16];
        const float u2 = 2.f*sb[2] + xs0*sih[2] + xs1*sih[7] + xs2*sih[12] + xs3*sih[17];
        const float u3 = 2.f*sb[3] + xs0*sih[3] + xs1*sih[8] + xs2*sih[13] + xs3*sih[18];
        const float u4 = 2.f*sb[4] + xs0*sih[4] + xs1*sih[9] + xs2*sih[14] + xs3*sih[19];
        contrib = u0*w0 + u1*w1 + u2*w2 + u3*w3 + u4*w4;
    }

    // wave64 shuffle reduce -> per-wave LDS -> one atomic per block
    #pragma unroll
    for (int off = 32; off > 0; off >>= 1)
        contrib += __shfl_down(contrib, off, 64);
    if ((tid & 63) == 0) red[tid >> 6] = contrib;
    __syncthreads();
    if (tid == 0) {
        const float blocksum = red[0] + red[1] + red[2] + red[3];
        atomicAdd(out, blocksum);
    }
}

extern "C" void kernel_launch(void* const* d_in, const int* in_sizes, int n_in,
                              void* d_out, int out_size, void* d_ws, size_t ws_size,
                              hipStream_t stream) {
    const float* x    = (const float*)d_in[0];
    const float* ih   = (const float*)d_in[1];
    const float* hh   = (const float*)d_in[2];
    const float* bias = (const float*)d_in[3];
    float* out = (float*)d_out;

    // Harness poisons d_out and does not re-zero between replays; the kernel
    // accumulates via atomicAdd, so zero the scalar first (capturable memset).
    hipMemsetAsync(out, 0, sizeof(float), stream);

    elman_sum_kernel<<<T_LEN / 256, 256, 0, stream>>>(x, ih, hh, bias, out);
}